// Round 3
// baseline (2291.304 us; speedup 1.0000x reference)
//
#include <hip/hip_runtime.h>
#include <stdint.h>

typedef __attribute__((ext_vector_type(4))) float f32x4;

#define T_WIN 4
#define BSZ   128
#define SSZ   64
#define DDIM  3136
#define FDIM  512
#define HDIM  512
#define LDIM  18
#define ROWS  8192   // B*S
#define KB    32

// ============================================================================
// fp32 SGEMM, C[M,N] = A[M,K] @ B[K,N], replicating OpenBLAS sgemm arithmetic
// bitwise: K is blocked into chunks (GEMM_Q=384, tail halving); each chunk is
// an ascending-k single-accumulator fma chain from zero; chunks are added
// sequentially into the running value (one rounded add each).
// Flush boundaries passed as bitmasks over k-tile index (k0/32).
// Tile: 128x128 per block, 256 threads, 8x8 outputs/thread.
// AMODE 0: A fp32;  AMODE 1: A uint8 (0/1 spikes -> exact products).
// ============================================================================
struct GArgs { const void* A; const float* B; float* C; int M; };

template<int AMODE>
__global__ __launch_bounds__(256, 2) void sgemm_kernel(GArgs g0, GArgs g1, GArgs g2,
                                                       int N, int K,
                                                       uint64_t bm_lo, uint64_t bm_hi) {
  GArgs g = g0;
  if (blockIdx.z == 1) g = g1;
  else if (blockIdx.z == 2) g = g2;
  const int m0 = blockIdx.x * 128;
  if (m0 >= g.M) return;              // uniform early-exit (small z-packed GEMMs)
  const int n0 = blockIdx.y * 128;

  __shared__ float sA[KB][132];       // [k][m]
  __shared__ float sB[KB][132];       // [k][n]

  const int tid = threadIdx.x;
  const int tx = tid & 15;            // n sub-tile (8 cols)
  const int ty = tid >> 4;            // m sub-tile (8 rows)

  // staging assignments
  const int am  = tid >> 1;           // A row 0..127
  const int aks = (tid & 1) * 16;     // A k-chunk (16 elements)
  const int br  = tid >> 3;           // B k-row 0..31
  const int bcs = (tid & 7) * 16;     // B col chunk (16 floats)

  const float*   Af = (const float*)g.A;
  const uint8_t* A8 = (const uint8_t*)g.A;

  float run[8][8], cur[8][8];
#pragma unroll
  for (int i = 0; i < 8; i++)
#pragma unroll
    for (int j = 0; j < 8; j++) { run[i][j] = 0.f; cur[i][j] = 0.f; }

  const int KT = K / KB;
  for (int kt = 0; kt < KT; kt++) {
    const int k0 = kt * KB;
    // ---- global -> regs ----
    f32x4 av[4];
    if (AMODE == 0) {
      const float* ap = Af + (size_t)(m0 + am) * K + k0 + aks;
#pragma unroll
      for (int c = 0; c < 4; c++) av[c] = *(const f32x4*)(ap + 4 * c);
    } else {
      const uint8_t* ap = A8 + (size_t)(m0 + am) * K + k0 + aks;
      uint4 wrd = *(const uint4*)ap;
      uint32_t u[4] = {wrd.x, wrd.y, wrd.z, wrd.w};
#pragma unroll
      for (int c = 0; c < 4; c++) {
        av[c][0] = (float)(u[c] & 255u);
        av[c][1] = (float)((u[c] >> 8) & 255u);
        av[c][2] = (float)((u[c] >> 16) & 255u);
        av[c][3] = (float)((u[c] >> 24) & 255u);
      }
    }
    f32x4 bv[4];
    const float* bp = g.B + (size_t)(k0 + br) * N + n0 + bcs;
#pragma unroll
    for (int c = 0; c < 4; c++) bv[c] = *(const f32x4*)(bp + 4 * c);

    __syncthreads();                  // previous iter's LDS reads done
#pragma unroll
    for (int c = 0; c < 4; c++)
#pragma unroll
      for (int j = 0; j < 4; j++)
        sA[aks + 4 * c + j][am] = av[c][j];
#pragma unroll
    for (int c = 0; c < 4; c++)
      *(f32x4*)&sB[br][bcs + 4 * c] = bv[c];
    __syncthreads();                  // tile ready

    // ---- OpenBLAS K-chunk boundary: run += cur; cur = 0 ----
    const bool fl = (kt < 64) ? (((bm_lo >> kt) & 1ull) != 0)
                              : (((bm_hi >> (kt - 64)) & 1ull) != 0);
    if (fl) {
#pragma unroll
      for (int i = 0; i < 8; i++)
#pragma unroll
        for (int j = 0; j < 8; j++) {
          run[i][j] = __fadd_rn(run[i][j], cur[i][j]);
          cur[i][j] = 0.f;
        }
    }

    // ---- inner k (ascending, single accumulator per output) ----
#pragma unroll 4
    for (int k = 0; k < KB; k++) {
      f32x4 a0 = *(const f32x4*)&sA[k][ty * 8];
      f32x4 a1 = *(const f32x4*)&sA[k][ty * 8 + 4];
      f32x4 b0 = *(const f32x4*)&sB[k][tx * 8];
      f32x4 b1 = *(const f32x4*)&sB[k][tx * 8 + 4];
      float a[8] = {a0[0], a0[1], a0[2], a0[3], a1[0], a1[1], a1[2], a1[3]};
      float b[8] = {b0[0], b0[1], b0[2], b0[3], b1[0], b1[1], b1[2], b1[3]};
#pragma unroll
      for (int i = 0; i < 8; i++)
#pragma unroll
        for (int j = 0; j < 8; j++)
          cur[i][j] = __fmaf_rn(a[i], b[j], cur[i][j]);
    }
  }

  // ---- final chunk flush + store ----
#pragma unroll
  for (int i = 0; i < 8; i++) {
    size_t rowoff = (size_t)(m0 + ty * 8 + i) * N + n0 + tx * 8;
#pragma unroll
    for (int j = 0; j < 2; j++) {
      f32x4 v;
#pragma unroll
      for (int c = 0; c < 4; c++)
        v[c] = __fadd_rn(run[i][4 * j + c], cur[i][4 * j + c]);
      *(f32x4*)(g.C + rowoff + 4 * j) = v;
    }
  }
}

// ============================================================================
// p/t leaky filters: post-update states P[t,b,f], Tf[t,b,f]; exact np op order.
// ============================================================================
__global__ __launch_bounds__(256) void filter_pt_kernel(const float* __restrict__ prox,
                                                        const float* __restrict__ trunk,
                                                        float* __restrict__ P,
                                                        float* __restrict__ Tf) {
  int idx = blockIdx.x * 256 + threadIdx.x;   // 16384: (b, f/4)
  int b = idx >> 7;
  int fc = (idx & 127) << 2;
  f32x4 p = {0.f, 0.f, 0.f, 0.f}, t = {0.f, 0.f, 0.f, 0.f};
  for (int tt = 0; tt < T_WIN; tt++) {
    size_t o = (size_t)(tt * BSZ + b) * FDIM + fc;
    f32x4 x = *(const f32x4*)&prox[o];
    f32x4 y = *(const f32x4*)&trunk[o];
#pragma unroll
    for (int c = 0; c < 4; c++) {
      p[c] = __fadd_rn(p[c], __fmul_rn(__fsub_rn(x[c], p[c]), 0.5f));
      t[c] = __fadd_rn(t[c], __fmul_rn(__fsub_rn(y[c], t[c]), 0.5f));
    }
    *(f32x4*)&P[o] = p;
    *(f32x4*)&Tf[o] = t;
  }
}

// ============================================================================
// soma LIF chain -> spike bytes (0/1) for all t; exact np op order (no fma
// contraction of p*d + t).
// ============================================================================
__global__ __launch_bounds__(256) void lif_soma_kernel(const float* __restrict__ dist,
                                                       const float* __restrict__ P,
                                                       const float* __restrict__ Tf,
                                                       uint8_t* __restrict__ emb) {
  int idx = blockIdx.x * 256 + threadIdx.x;   // 1,048,576: (r, f/4)
  int r = idx >> 7;
  int fc = (idx & 127) << 2;
  int b = r >> 6;
  f32x4 d = {0.f, 0.f, 0.f, 0.f}, soma = {0.f, 0.f, 0.f, 0.f};
#pragma unroll
  for (int t = 0; t < T_WIN; t++) {
    f32x4 x  = *(const f32x4*)&dist[(size_t)(t * ROWS + r) * FDIM + fc];
    f32x4 pv = *(const f32x4*)&P[(size_t)(t * BSZ + b) * FDIM + fc];
    f32x4 tv = *(const f32x4*)&Tf[(size_t)(t * BSZ + b) * FDIM + fc];
    uint32_t bits = 0;
#pragma unroll
    for (int c = 0; c < 4; c++) {
      d[c] = __fadd_rn(d[c], __fmul_rn(__fsub_rn(x[c], d[c]), 0.5f));
      float pd = __fmul_rn(pv[c], d[c]);          // p*d (must NOT contract)
      float u  = __fadd_rn(pd, tv[c]);            // + t
      float w  = __fsub_rn(u, soma[c]);           // - soma
      soma[c] = __fadd_rn(soma[c], __fmul_rn(w, 0.5f));
      if (soma[c] >= 0.5f) { bits |= (1u << (8 * c)); soma[c] = 0.f; }
    }
    *(uint32_t*)&emb[(size_t)(t * ROWS + r) * FDIM + fc] = bits;
  }
}

// ============================================================================
// hidden LIF chain -> spike counts (u8, 0..4); exact op order; b1 added first.
// ============================================================================
__global__ __launch_bounds__(256) void lif_hidden_kernel(const float* __restrict__ H,
                                                         const float* __restrict__ b1,
                                                         uint8_t* __restrict__ cnt) {
  int idx = blockIdx.x * 256 + threadIdx.x;   // (r, f/4)
  int r = idx >> 7;
  int fc = (idx & 127) << 2;
  f32x4 bb = *(const f32x4*)&b1[fc];
  f32x4 lif = {0.f, 0.f, 0.f, 0.f};
  uint32_t counts = 0;
#pragma unroll
  for (int t = 0; t < T_WIN; t++) {
    f32x4 h = *(const f32x4*)&H[(size_t)(t * ROWS + r) * FDIM + fc];
#pragma unroll
    for (int c = 0; c < 4; c++) {
      float hv = __fadd_rn(h[c], bb[c]);
      lif[c] = __fadd_rn(lif[c], __fmul_rn(__fsub_rn(hv, lif[c]), 0.5f));
      if (lif[c] >= 0.5f) { counts += (1u << (8 * c)); lif[c] = 0.f; }
    }
  }
  *(uint32_t*)&cnt[(size_t)r * FDIM + fc] = counts;
}

// ============================================================================
// out[b,l,s] = sum_k (cnt[r,k]/4)*W2[k,l] + b2[l]; post-spike continuous math,
// reorder-safe (deviation ~1e-7 << 2.8e-3 threshold). Final output only.
// ============================================================================
__global__ __launch_bounds__(256) void out_kernel(const uint8_t* __restrict__ cnt,
                                                  const float* __restrict__ W2,
                                                  const float* __restrict__ b2,
                                                  float* __restrict__ out) {
  int idx = blockIdx.x * 256 + threadIdx.x;   // 147456 = 8192*18
  int r = idx / LDIM;
  int j = idx - r * LDIM;
  const uint8_t* crow = cnt + (size_t)r * HDIM;
  float acc = 0.f;
  for (int k = 0; k < HDIM; k++) {
    uint32_t c = crow[k];
    if (c) acc = __fmaf_rn((float)c * 0.25f, W2[k * LDIM + j], acc);
  }
  int b = r >> 6, s = r & 63;
  out[(size_t)b * (LDIM * SSZ) + j * SSZ + s] = __fadd_rn(acc, b2[j]);
}

// ---------- workspace layout (88 MB) ----------
// dist_all / H_all fp32  @ 0          (67,108,864)
// emb8 u8                @ 67,108,864 (16,777,216)
// cnt8 u8                @ 83,886,080 ( 4,194,304)
// prox_raw fp32          @ 88,080,384 ( 1,048,576)
// trunk_raw fp32         @ 89,128,960 ( 1,048,576)
// P fp32                 @ 90,177,536 ( 1,048,576)
// Tf fp32                @ 91,226,112 ( 1,048,576)  -> total 92,274,688

extern "C" void kernel_launch(void* const* d_in, const int* in_sizes, int n_in,
                              void* d_out, int out_size, void* d_ws, size_t ws_size,
                              hipStream_t stream) {
  const float* se     = (const float*)d_in[0];
  const float* te     = (const float*)d_in[1];
  const float* ee     = (const float*)d_in[2];
  const float* Wprox  = (const float*)d_in[3];
  const float* Wdist  = (const float*)d_in[4];
  const float* Wtrunk = (const float*)d_in[5];
  const float* W1     = (const float*)d_in[6];
  const float* b1     = (const float*)d_in[7];
  const float* W2     = (const float*)d_in[8];
  const float* b2     = (const float*)d_in[9];

  char* ws = (char*)d_ws;
  float*   dist_all  = (float*)(ws);                 // later reused as H_all
  uint8_t* emb8      = (uint8_t*)(ws + 67108864);
  uint8_t* cnt8      = (uint8_t*)(ws + 83886080);
  float*   prox_raw  = (float*)(ws + 88080384);
  float*   trunk_raw = (float*)(ws + 89128960);
  float*   P         = (float*)(ws + 90177536);
  float*   Tf        = (float*)(ws + 91226112);

  // OpenBLAS K-chunk flush masks over k-tile index (k0/32):
  // K=3136 -> chunks {384x7, 224, 224}: boundaries at tiles 12,24,36,48,60 | 72,84,91
  const uint64_t bm3136_lo = (1ull << 12) | (1ull << 24) | (1ull << 36) |
                             (1ull << 48) | (1ull << 60);
  const uint64_t bm3136_hi = (1ull << (72 - 64)) | (1ull << (84 - 64)) | (1ull << (91 - 64));
  // K=512 -> chunks {256,256}: boundary at tile 8
  const uint64_t bm512_lo = (1ull << 8);

  // 1. batched input GEMMs (z=0: dist 32768x3136x512; z=1/2: prox/trunk 512x...)
  GArgs gd{te, Wdist, dist_all, T_WIN * ROWS};
  GArgs gp{se, Wprox, prox_raw, T_WIN * BSZ};
  GArgs gt{ee, Wtrunk, trunk_raw, T_WIN * BSZ};
  sgemm_kernel<0><<<dim3(256, 4, 3), 256, 0, stream>>>(gd, gp, gt, FDIM, DDIM,
                                                       bm3136_lo, bm3136_hi);

  // 2. p/t filters (exact chains)
  filter_pt_kernel<<<64, 256, 0, stream>>>(prox_raw, trunk_raw, P, Tf);

  // 3. soma LIF -> binary spikes (u8)
  lif_soma_kernel<<<4096, 256, 0, stream>>>(dist_all, P, Tf, emb8);

  // 4. H = emb @ W1, all t batched (overwrites dist_all, dead)
  GArgs gh{emb8, W1, dist_all, T_WIN * ROWS};
  sgemm_kernel<1><<<dim3(256, 4, 1), 256, 0, stream>>>(gh, gh, gh, HDIM, FDIM,
                                                       bm512_lo, 0ull);

  // 5. hidden LIF -> spike counts
  lif_hidden_kernel<<<4096, 256, 0, stream>>>(dist_all, b1, cnt8);

  // 6. output GEMM + b2 + [B,LAST,S] transpose, fp32
  out_kernel<<<576, 256, 0, stream>>>(cnt8, W2, b2, (float*)d_out);
}